// Round 4
// baseline (1528.259 us; speedup 1.0000x reference)
//
#include <hip/hip_runtime.h>
#include <hip/hip_bf16.h>

// GCN 2-layer: h1 = relu(Ahat @ (x@W1) + b1); out = Ahat @ (h1@W2) + b2
// Ahat = D^-1/2 (A + I) D^-1/2.
//
// Edge handling: deterministic bucket partition (bucket = dst>>6, 782 buckets),
// built with per-block LDS histograms + scans -- ZERO global atomics (R3's
// per-bucket global atomic cursor serialized 2046 atomics/address = 376 us).
// Aggregation is per-bucket: 64 nodes x 64 ch accumulated in LDS via
// ds_add_f32. No per-node CSR needed. Edge records packed to 4 B:
// src | (dst&63)<<16  (requires n < 65536; here n = 50000).

#define NB_MAX 1024  // buckets (n<=65536)

// ---- 1. per-block bucket histogram ----------------------------------------

__global__ __launch_bounds__(256) void k_hist(const int* __restrict__ ei, int E,
                                              int nb, int chunk,
                                              int* __restrict__ histT) {
    __shared__ int h[NB_MAX];
    for (int i = threadIdx.x; i < nb; i += 256) h[i] = 0;
    __syncthreads();
    int e0 = blockIdx.x * chunk, e1 = min(E, e0 + chunk);
    for (int e = e0 + threadIdx.x; e < e1; e += 256)
        atomicAdd(&h[ei[E + e] >> 6], 1);          // LDS atomic
    __syncthreads();
    for (int b = threadIdx.x; b < nb; b += 256)
        histT[b * 256 + blockIdx.x] = h[b];        // [bucket][block]
}

// ---- 2. scan each bucket's 256 per-block counts ---------------------------

__global__ __launch_bounds__(256) void k_scan_cols(int* __restrict__ histT,
                                                   int* __restrict__ total) {
    __shared__ int sm[256];
    int b = blockIdx.x, t = threadIdx.x;
    int v = histT[b * 256 + t];
    sm[t] = v;
    __syncthreads();
    for (int off = 1; off < 256; off <<= 1) {
        int u = (t >= off) ? sm[t - off] : 0;
        __syncthreads();
        sm[t] += u;
        __syncthreads();
    }
    histT[b * 256 + t] = sm[t] - v;                // exclusive within bucket
    if (t == 255) total[b] = sm[255];
}

// ---- 3. scan bucket totals -> bucket bases --------------------------------

__global__ __launch_bounds__(1024) void k_scan_totals(const int* __restrict__ total,
                                                      int* __restrict__ base, int nb) {
    __shared__ int sm[1024];
    int t = threadIdx.x;
    int v = (t < nb) ? total[t] : 0;
    sm[t] = v;
    __syncthreads();
    for (int off = 1; off < 1024; off <<= 1) {
        int u = (t >= off) ? sm[t - off] : 0;
        __syncthreads();
        sm[t] += u;
        __syncthreads();
    }
    if (t < nb) base[t] = sm[t] - v;               // exclusive
    if (t == nb - 1) base[nb] = sm[t];             // total E
}

// ---- 4. scatter packed edges into bucket-grouped order --------------------

__global__ __launch_bounds__(256) void k_scatter(const int* __restrict__ ei, int E,
                                                 int nb, int chunk,
                                                 const int* __restrict__ histT,
                                                 const int* __restrict__ base,
                                                 unsigned* __restrict__ packed) {
    __shared__ int cur[NB_MAX];
    for (int b = threadIdx.x; b < nb; b += 256)
        cur[b] = base[b] + histT[b * 256 + blockIdx.x];
    __syncthreads();
    int e0 = blockIdx.x * chunk, e1 = min(E, e0 + chunk);
    for (int e = e0 + threadIdx.x; e < e1; e += 256) {
        int s = ei[e], d = ei[E + e];
        int pos = atomicAdd(&cur[d >> 6], 1);      // LDS atomic
        packed[pos] = (unsigned)s | ((unsigned)(d & 63) << 16);
    }
}

// ---- 5. per-node degree -> dinv (from packed, per bucket) -----------------

__global__ __launch_bounds__(256) void k_degdinv(const unsigned* __restrict__ packed,
                                                 const int* __restrict__ base,
                                                 int n, float* __restrict__ dinv) {
    __shared__ int cnt[64];
    int b = blockIdx.x, t = threadIdx.x;
    if (t < 64) cnt[t] = 0;
    __syncthreads();
    int p0 = base[b], p1 = base[b + 1];
    for (int p = p0 + t; p < p1; p += 256)
        atomicAdd(&cnt[(packed[p] >> 16) & 63], 1);
    __syncthreads();
    if (t < 64) {
        int node = (b << 6) + t;
        if (node < n) dinv[node] = 1.0f / sqrtf((float)(cnt[t] + 1));  // +1 self-loop
    }
}

// ---- GEMM: HS[n,64] = dinv[:,None] * (X[n,K] @ W[K,64]) --------------------
// Register-tiled: block(256) = 64x64 tile; thread = 4x4. dinv pre-scale fused.

#define FMA4(A, s, wv)                                                         \
    (A).x += (s) * (wv).x; (A).y += (s) * (wv).y;                              \
    (A).z += (s) * (wv).z; (A).w += (s) * (wv).w;

template <int K>
__global__ __launch_bounds__(256) void k_gemm(const float* __restrict__ X,
                                              const float* __restrict__ W,
                                              const float* __restrict__ dinv,
                                              float* __restrict__ HS, int n) {
    __shared__ float xl[64][36];
    __shared__ float wl[32][64];

    const int t = threadIdx.x;
    const int tc = t & 15;
    const int tr = t >> 4;
    const int row0 = blockIdx.x * 64;

    float4 acc[4];
    acc[0] = acc[1] = acc[2] = acc[3] = make_float4(0.f, 0.f, 0.f, 0.f);

    for (int k0 = 0; k0 < K; k0 += 32) {
#pragma unroll
        for (int i = 0; i < 2; ++i) {
            int idx = i * 256 + t;
            int r = idx >> 3, f4 = idx & 7;
            int gr = row0 + r;
            float4 v = make_float4(0.f, 0.f, 0.f, 0.f);
            if (gr < n) v = *(const float4*)(X + (size_t)gr * K + k0 + f4 * 4);
            *(float4*)&xl[r][f4 * 4] = v;
        }
#pragma unroll
        for (int i = 0; i < 2; ++i) {
            int idx = i * 256 + t;
            int kr = idx >> 4, f4 = idx & 15;
            *(float4*)&wl[kr][f4 * 4] =
                *(const float4*)(W + (size_t)(k0 + kr) * 64 + f4 * 4);
        }
        __syncthreads();

#pragma unroll
        for (int kk = 0; kk < 32; kk += 4) {
            float4 xv0 = *(float4*)&xl[tr * 4 + 0][kk];
            float4 xv1 = *(float4*)&xl[tr * 4 + 1][kk];
            float4 xv2 = *(float4*)&xl[tr * 4 + 2][kk];
            float4 xv3 = *(float4*)&xl[tr * 4 + 3][kk];
            float4 wv0 = *(float4*)&wl[kk + 0][tc * 4];
            float4 wv1 = *(float4*)&wl[kk + 1][tc * 4];
            float4 wv2 = *(float4*)&wl[kk + 2][tc * 4];
            float4 wv3 = *(float4*)&wl[kk + 3][tc * 4];

            FMA4(acc[0], xv0.x, wv0); FMA4(acc[0], xv0.y, wv1);
            FMA4(acc[0], xv0.z, wv2); FMA4(acc[0], xv0.w, wv3);
            FMA4(acc[1], xv1.x, wv0); FMA4(acc[1], xv1.y, wv1);
            FMA4(acc[1], xv1.z, wv2); FMA4(acc[1], xv1.w, wv3);
            FMA4(acc[2], xv2.x, wv0); FMA4(acc[2], xv2.y, wv1);
            FMA4(acc[2], xv2.z, wv2); FMA4(acc[2], xv2.w, wv3);
            FMA4(acc[3], xv3.x, wv0); FMA4(acc[3], xv3.y, wv1);
            FMA4(acc[3], xv3.z, wv2); FMA4(acc[3], xv3.w, wv3);
        }
        __syncthreads();
    }

#pragma unroll
    for (int ri = 0; ri < 4; ++ri) {
        int gr = row0 + tr * 4 + ri;
        if (gr < n) {
            float dv = dinv[gr];
            float4 o = acc[ri];
            o.x *= dv; o.y *= dv; o.z *= dv; o.w *= dv;
            *(float4*)(HS + (size_t)gr * 64 + tc * 4) = o;
        }
    }
}

// ---- 6. bucket aggregation: out[i] = dinv[i]*(sum hs[src] + hs[i]) + b ----
// Block per bucket; LDS acc[64 nodes][64 ch]; ds_add_f32 accumulation.
// Waves process quads of pairs -> 4 gathers in flight per wave.

template <bool RELU>
__global__ __launch_bounds__(256) void k_aggb(const float* __restrict__ hs,
                                              const unsigned* __restrict__ packed,
                                              const int* __restrict__ base,
                                              const float* __restrict__ dinv,
                                              const float* __restrict__ bias,
                                              float* __restrict__ out, int n) {
    __shared__ float acc[64][64];
    const int t = threadIdx.x;
    for (int i = t; i < 64 * 64; i += 256) ((float*)acc)[i] = 0.f;
    __syncthreads();

    const int b = blockIdx.x;
    const int lane = t & 63, wid = t >> 6;
    const int p0 = base[b], p1 = base[b + 1];

    int p = p0 + wid * 4;
    for (; p + 3 < p1; p += 16) {                  // full quads, round-robin waves
        unsigned k0 = packed[p + 0], k1 = packed[p + 1];
        unsigned k2 = packed[p + 2], k3 = packed[p + 3];
        float v0 = hs[(size_t)(k0 & 0xFFFFu) * 64 + lane];
        float v1 = hs[(size_t)(k1 & 0xFFFFu) * 64 + lane];
        float v2 = hs[(size_t)(k2 & 0xFFFFu) * 64 + lane];
        float v3 = hs[(size_t)(k3 & 0xFFFFu) * 64 + lane];
        atomicAdd(&acc[(k0 >> 16) & 63][lane], v0);
        atomicAdd(&acc[(k1 >> 16) & 63][lane], v1);
        atomicAdd(&acc[(k2 >> 16) & 63][lane], v2);
        atomicAdd(&acc[(k3 >> 16) & 63][lane], v3);
    }
    if (p < p1) {                                  // final (partial) quad owner
        int pe = min(p + 4, p1);
        for (; p < pe; ++p) {
            unsigned k = packed[p];
            atomicAdd(&acc[(k >> 16) & 63][lane],
                      hs[(size_t)(k & 0xFFFFu) * 64 + lane]);
        }
    }
    __syncthreads();

    for (int i = t; i < 64 * 64; i += 256) {       // epilogue, coalesced
        int n6 = i >> 6, c = i & 63;
        int node = (b << 6) + n6;
        if (node < n) {
            float r = dinv[node] * (acc[n6][c] + hs[(size_t)node * 64 + c]) + bias[c];
            if (RELU) r = fmaxf(r, 0.f);
            out[(size_t)node * 64 + c] = r;
        }
    }
}

// ---- launch ----------------------------------------------------------------

extern "C" void kernel_launch(void* const* d_in, const int* in_sizes, int n_in,
                              void* d_out, int out_size, void* d_ws, size_t ws_size,
                              hipStream_t stream) {
    const float* x  = (const float*)d_in[0];
    const int*   ei = (const int*)d_in[1];
    const float* W1 = (const float*)d_in[2];
    const float* b1 = (const float*)d_in[3];
    const float* W2 = (const float*)d_in[4];
    const float* b2 = (const float*)d_in[5];

    const int n = in_sizes[0] / 256;   // 50000  (must be < 65536 for packing)
    const int E = in_sizes[1] / 2;     // 1600000
    const int nb = (n + 63) >> 6;      // 782 buckets
    const int chunk = (E + 255) / 256; // edges per histogram/scatter block

    // workspace carve-up (256B aligned)
    char* ws = (char*)d_ws;
    auto carve = [&](size_t bytes) {
        void* p = (void*)ws;
        ws += (bytes + 255) & ~(size_t)255;
        return p;
    };
    int*      histT  = (int*)carve((size_t)nb * 256 * 4);
    int*      total  = (int*)carve((size_t)nb * 4);
    int*      base   = (int*)carve((size_t)(nb + 1) * 4);
    unsigned* packed = (unsigned*)carve((size_t)E * 4);
    float*    dinv   = (float*)carve((size_t)n * 4);
    float*    hA     = (float*)carve((size_t)n * 64 * 4);
    float*    hB     = (float*)carve((size_t)n * 64 * 4);

    k_hist<<<256, 256, 0, stream>>>(ei, E, nb, chunk, histT);
    k_scan_cols<<<nb, 256, 0, stream>>>(histT, total);
    k_scan_totals<<<1, 1024, 0, stream>>>(total, base, nb);
    k_scatter<<<256, 256, 0, stream>>>(ei, E, nb, chunk, histT, base, packed);
    k_degdinv<<<nb, 256, 0, stream>>>(packed, base, n, dinv);

    const int nbG = (n + 63) / 64;

    // layer 1: hA = dinv*(x@W1) ; hB = relu(agg + b1)
    k_gemm<256><<<nbG, 256, 0, stream>>>(x, W1, dinv, hA, n);
    k_aggb<true><<<nb, 256, 0, stream>>>(hA, packed, base, dinv, b1, hB, n);

    // layer 2: hA = dinv*(hB@W2) ; out = agg + b2
    k_gemm<64><<<nbG, 256, 0, stream>>>(hB, W2, dinv, hA, n);
    k_aggb<false><<<nb, 256, 0, stream>>>(hA, packed, base, dinv, b2,
                                          (float*)d_out, n);
}

// Round 6
// 284.137 us; speedup vs baseline: 5.3786x; 5.3786x over previous
//
#include <hip/hip_runtime.h>
#include <hip/hip_bf16.h>

// GCN 2-layer: h1 = relu(Ahat @ (x@W1) + b1); out = Ahat @ (h1@W2) + b2
// Ahat = D^-1/2 (A + I) D^-1/2.
//
// Pipeline (zero global atomics):
//   k_hist/k_scan_cols/k_scan_totals/k_scatter: deterministic bucket partition
//     (bucket = dst>>6, 782 buckets) via per-block LDS histograms.
//   k_csr: per bucket -> per-node offsets (offs), dinv, and node-ordered
//     ushort src list (ssrc). Scatter confined to ~4 KB L2 window.
//   k_gemm: register-tiled 64x64, epilogue scales rows by dinv (hs = dinv*h).
//   k_agg: wave per node, lane = channel, 8 gathers in flight, no atomics.
//     out[i] = dinv[i]*(sum_src hs[src] + hs[i]) + b.
// R3 lesson: never funnel E atomics into few global addresses (376 us).
// R4 lesson: agg needs a huge grid + deep MLP, not per-bucket LDS atomics.
// R5 lesson: s_barrier is workgroup-scope -- never inside `if (t<64)`.
//            64-wide scan within one wave uses __shfl_up, no barrier.

#define NB_MAX 1024  // max buckets (n <= 65536 for ushort src packing)

// ---- 1. per-block bucket histogram ----------------------------------------

__global__ __launch_bounds__(256) void k_hist(const int* __restrict__ ei, int E,
                                              int nb, int chunk,
                                              int* __restrict__ histT) {
    __shared__ int h[NB_MAX];
    for (int i = threadIdx.x; i < nb; i += 256) h[i] = 0;
    __syncthreads();
    int e0 = blockIdx.x * chunk, e1 = min(E, e0 + chunk);
    for (int e = e0 + threadIdx.x; e < e1; e += 256)
        atomicAdd(&h[ei[E + e] >> 6], 1);          // LDS atomic
    __syncthreads();
    for (int b = threadIdx.x; b < nb; b += 256)
        histT[b * 256 + blockIdx.x] = h[b];        // [bucket][block]
}

// ---- 2. scan each bucket's 256 per-block counts ---------------------------

__global__ __launch_bounds__(256) void k_scan_cols(int* __restrict__ histT,
                                                   int* __restrict__ total) {
    __shared__ int sm[256];
    int b = blockIdx.x, t = threadIdx.x;
    int v = histT[b * 256 + t];
    sm[t] = v;
    __syncthreads();
    for (int off = 1; off < 256; off <<= 1) {
        int u = (t >= off) ? sm[t - off] : 0;
        __syncthreads();
        sm[t] += u;
        __syncthreads();
    }
    histT[b * 256 + t] = sm[t] - v;                // exclusive within bucket
    if (t == 255) total[b] = sm[255];
}

// ---- 3. scan bucket totals -> bucket bases --------------------------------

__global__ __launch_bounds__(1024) void k_scan_totals(const int* __restrict__ total,
                                                      int* __restrict__ base, int nb) {
    __shared__ int sm[1024];
    int t = threadIdx.x;
    int v = (t < nb) ? total[t] : 0;
    sm[t] = v;
    __syncthreads();
    for (int off = 1; off < 1024; off <<= 1) {
        int u = (t >= off) ? sm[t - off] : 0;
        __syncthreads();
        sm[t] += u;
        __syncthreads();
    }
    if (t < nb) base[t] = sm[t] - v;               // exclusive
    if (t == nb - 1) base[nb] = sm[t];             // total E
}

// ---- 4. scatter packed edges into bucket-grouped order --------------------

__global__ __launch_bounds__(256) void k_scatter(const int* __restrict__ ei, int E,
                                                 int nb, int chunk,
                                                 const int* __restrict__ histT,
                                                 const int* __restrict__ base,
                                                 unsigned* __restrict__ packed) {
    __shared__ int cur[NB_MAX];
    for (int b = threadIdx.x; b < nb; b += 256)
        cur[b] = base[b] + histT[b * 256 + blockIdx.x];
    __syncthreads();
    int e0 = blockIdx.x * chunk, e1 = min(E, e0 + chunk);
    for (int e = e0 + threadIdx.x; e < e1; e += 256) {
        int s = ei[e], d = ei[E + e];
        int pos = atomicAdd(&cur[d >> 6], 1);      // LDS atomic
        packed[pos] = (unsigned)s | ((unsigned)(d & 63) << 16);
    }
}

// ---- 5. per-bucket CSR: offs, dinv, node-ordered ushort src list ----------

__global__ __launch_bounds__(256) void k_csr(const unsigned* __restrict__ packed,
                                             const int* __restrict__ base, int n,
                                             int* __restrict__ offs,
                                             float* __restrict__ dinv,
                                             unsigned short* __restrict__ ssrc) {
    __shared__ int cnt[64];
    __shared__ int cur[64];
    const int b = blockIdx.x, t = threadIdx.x;
    const int p0 = base[b], p1 = base[b + 1];
    if (t < 64) cnt[t] = 0;
    __syncthreads();
    for (int p = p0 + t; p < p1; p += 256)
        atomicAdd(&cnt[(packed[p] >> 16) & 63], 1);
    __syncthreads();
    if (t < 64) {                      // threads 0..63 == wave 0: shuffle scan,
        int s = cnt[t];                // no barrier (R5 crash: s_barrier here)
        int sum = s;
#pragma unroll
        for (int d = 1; d < 64; d <<= 1) {
            int u = __shfl_up(sum, d, 64);
            if (t >= d) sum += u;
        }
        int excl = sum - s;            // exclusive scan
        int node = (b << 6) + t;
        if (node < n) {
            offs[node] = p0 + excl;
            dinv[node] = 1.0f / sqrtf((float)(s + 1));  // +1 self-loop
        }
        cur[t] = p0 + excl;
    }
    if (b == 0 && t == 0) offs[n] = base[(n + 63) >> 6];  // = E
    __syncthreads();
    for (int p = p0 + t; p < p1; p += 256) {
        unsigned k = packed[p];
        int pos = atomicAdd(&cur[(k >> 16) & 63], 1);
        ssrc[pos] = (unsigned short)(k & 0xFFFFu); // ~4 KB window scatter
    }
}

// ---- GEMM: HS[n,64] = dinv[:,None] * (X[n,K] @ W[K,64]) --------------------
// Register-tiled: block(256) = 64x64 tile; thread = 4x4. dinv pre-scale fused.

#define FMA4(A, s, wv)                                                         \
    (A).x += (s) * (wv).x; (A).y += (s) * (wv).y;                              \
    (A).z += (s) * (wv).z; (A).w += (s) * (wv).w;

template <int K>
__global__ __launch_bounds__(256) void k_gemm(const float* __restrict__ X,
                                              const float* __restrict__ W,
                                              const float* __restrict__ dinv,
                                              float* __restrict__ HS, int n) {
    __shared__ float xl[64][36];
    __shared__ float wl[32][64];

    const int t = threadIdx.x;
    const int tc = t & 15;
    const int tr = t >> 4;
    const int row0 = blockIdx.x * 64;

    float4 acc[4];
    acc[0] = acc[1] = acc[2] = acc[3] = make_float4(0.f, 0.f, 0.f, 0.f);

    for (int k0 = 0; k0 < K; k0 += 32) {
#pragma unroll
        for (int i = 0; i < 2; ++i) {
            int idx = i * 256 + t;
            int r = idx >> 3, f4 = idx & 7;
            int gr = row0 + r;
            float4 v = make_float4(0.f, 0.f, 0.f, 0.f);
            if (gr < n) v = *(const float4*)(X + (size_t)gr * K + k0 + f4 * 4);
            *(float4*)&xl[r][f4 * 4] = v;
        }
#pragma unroll
        for (int i = 0; i < 2; ++i) {
            int idx = i * 256 + t;
            int kr = idx >> 4, f4 = idx & 15;
            *(float4*)&wl[kr][f4 * 4] =
                *(const float4*)(W + (size_t)(k0 + kr) * 64 + f4 * 4);
        }
        __syncthreads();

#pragma unroll
        for (int kk = 0; kk < 32; kk += 4) {
            float4 xv0 = *(float4*)&xl[tr * 4 + 0][kk];
            float4 xv1 = *(float4*)&xl[tr * 4 + 1][kk];
            float4 xv2 = *(float4*)&xl[tr * 4 + 2][kk];
            float4 xv3 = *(float4*)&xl[tr * 4 + 3][kk];
            float4 wv0 = *(float4*)&wl[kk + 0][tc * 4];
            float4 wv1 = *(float4*)&wl[kk + 1][tc * 4];
            float4 wv2 = *(float4*)&wl[kk + 2][tc * 4];
            float4 wv3 = *(float4*)&wl[kk + 3][tc * 4];

            FMA4(acc[0], xv0.x, wv0); FMA4(acc[0], xv0.y, wv1);
            FMA4(acc[0], xv0.z, wv2); FMA4(acc[0], xv0.w, wv3);
            FMA4(acc[1], xv1.x, wv0); FMA4(acc[1], xv1.y, wv1);
            FMA4(acc[1], xv1.z, wv2); FMA4(acc[1], xv1.w, wv3);
            FMA4(acc[2], xv2.x, wv0); FMA4(acc[2], xv2.y, wv1);
            FMA4(acc[2], xv2.z, wv2); FMA4(acc[2], xv2.w, wv3);
            FMA4(acc[3], xv3.x, wv0); FMA4(acc[3], xv3.y, wv1);
            FMA4(acc[3], xv3.z, wv2); FMA4(acc[3], xv3.w, wv3);
        }
        __syncthreads();
    }

#pragma unroll
    for (int ri = 0; ri < 4; ++ri) {
        int gr = row0 + tr * 4 + ri;
        if (gr < n) {
            float dv = dinv[gr];
            float4 o = acc[ri];
            o.x *= dv; o.y *= dv; o.z *= dv; o.w *= dv;
            *(float4*)(HS + (size_t)gr * 64 + tc * 4) = o;
        }
    }
}

// ---- 6. aggregation: out[i] = dinv[i]*(sum_src hs[src] + hs[i]) + b -------
// Wave per node, lane = channel. 8 coalesced 256B gathers in flight. No atomics.

template <bool RELU>
__global__ void k_agg(const float* __restrict__ hs,
                      const int* __restrict__ offs,
                      const unsigned short* __restrict__ ssrc,
                      const float* __restrict__ dinv,
                      const float* __restrict__ bias,
                      float* __restrict__ out, int n) {
    int node = blockIdx.x * 4 + (threadIdx.x >> 6);
    if (node >= n) return;
    int lane = threadIdx.x & 63;

    int beg = offs[node];
    int end = offs[node + 1];
    float acc = hs[(size_t)node * 64 + lane];      // self-loop (pre-scaled)

    int p = beg;
    for (; p + 7 < end; p += 8) {
        int s0 = ssrc[p + 0], s1 = ssrc[p + 1], s2 = ssrc[p + 2], s3 = ssrc[p + 3];
        int s4 = ssrc[p + 4], s5 = ssrc[p + 5], s6 = ssrc[p + 6], s7 = ssrc[p + 7];
        float v0 = hs[(size_t)s0 * 64 + lane];
        float v1 = hs[(size_t)s1 * 64 + lane];
        float v2 = hs[(size_t)s2 * 64 + lane];
        float v3 = hs[(size_t)s3 * 64 + lane];
        float v4 = hs[(size_t)s4 * 64 + lane];
        float v5 = hs[(size_t)s5 * 64 + lane];
        float v6 = hs[(size_t)s6 * 64 + lane];
        float v7 = hs[(size_t)s7 * 64 + lane];
        acc += ((v0 + v1) + (v2 + v3)) + ((v4 + v5) + (v6 + v7));
    }
    for (; p < end; ++p)
        acc += hs[(size_t)ssrc[p] * 64 + lane];

    float r = dinv[node] * acc + bias[lane];
    if (RELU) r = fmaxf(r, 0.0f);
    out[(size_t)node * 64 + lane] = r;
}

// ---- launch ----------------------------------------------------------------

extern "C" void kernel_launch(void* const* d_in, const int* in_sizes, int n_in,
                              void* d_out, int out_size, void* d_ws, size_t ws_size,
                              hipStream_t stream) {
    const float* x  = (const float*)d_in[0];
    const int*   ei = (const int*)d_in[1];
    const float* W1 = (const float*)d_in[2];
    const float* b1 = (const float*)d_in[3];
    const float* W2 = (const float*)d_in[4];
    const float* b2 = (const float*)d_in[5];

    const int n = in_sizes[0] / 256;   // 50000 (< 65536: ushort src packing)
    const int E = in_sizes[1] / 2;     // 1600000
    const int nb = (n + 63) >> 6;      // 782 buckets
    const int chunk = (E + 255) / 256;

    // workspace carve-up (256B aligned)
    char* ws = (char*)d_ws;
    auto carve = [&](size_t bytes) {
        void* p = (void*)ws;
        ws += (bytes + 255) & ~(size_t)255;
        return p;
    };
    int*            histT  = (int*)carve((size_t)nb * 256 * 4);
    int*            total  = (int*)carve((size_t)nb * 4);
    int*            base   = (int*)carve((size_t)(nb + 1) * 4);
    unsigned*       packed = (unsigned*)carve((size_t)E * 4);
    unsigned short* ssrc   = (unsigned short*)carve((size_t)E * 2);
    int*            offs   = (int*)carve((size_t)(n + 1) * 4);
    float*          dinv   = (float*)carve((size_t)n * 4);
    float*          hA     = (float*)carve((size_t)n * 64 * 4);
    float*          hB     = (float*)carve((size_t)n * 64 * 4);

    k_hist<<<256, 256, 0, stream>>>(ei, E, nb, chunk, histT);
    k_scan_cols<<<nb, 256, 0, stream>>>(histT, total);
    k_scan_totals<<<1, 1024, 0, stream>>>(total, base, nb);
    k_scatter<<<256, 256, 0, stream>>>(ei, E, nb, chunk, histT, base, packed);
    k_csr<<<nb, 256, 0, stream>>>(packed, base, n, offs, dinv, ssrc);

    const int nbG = (n + 63) / 64;

    // layer 1: hA = dinv*(x@W1) ; hB = relu(agg + b1)
    k_gemm<256><<<nbG, 256, 0, stream>>>(x, W1, dinv, hA, n);
    k_agg<true><<<(n + 3) / 4, 256, 0, stream>>>(hA, offs, ssrc, dinv, b1, hB, n);

    // layer 2: hA = dinv*(hB@W2) ; out = agg + b2
    k_gemm<64><<<nbG, 256, 0, stream>>>(hB, W2, dinv, hA, n);
    k_agg<false><<<(n + 3) / 4, 256, 0, stream>>>(hA, offs, ssrc, dinv, b2,
                                                  (float*)d_out, n);
}

// Round 7
// 263.653 us; speedup vs baseline: 5.7965x; 1.0777x over previous
//
#include <hip/hip_runtime.h>
#include <hip/hip_bf16.h>

// GCN 2-layer: h1 = relu(Ahat @ (x@W1) + b1); out = Ahat @ (h1@W2) + b2
// Ahat = D^-1/2 (A + I) D^-1/2.
//
// Pipeline (zero global atomics):
//   k_hist/k_scan_cols/k_scan_totals/k_scatter: deterministic bucket partition
//     (bucket = dst>>6, 782 buckets) via per-block LDS histograms.
//   k_csr: per bucket -> per-node offsets (offs), dinv, node-ordered ushort src.
//   k_gemm: register-tiled 64x64; epilogue writes hs = bf16(dinv * (X@W)).
//   k_agg: wave per node, lane = channel, 8 bf16 gathers in flight, no atomics.
//     out[i] = dinv[i]*(sum_src hs[src] + hs[i]) + b   (fp32 accumulate).
// R3 lesson: never funnel E atomics into few global addresses.
// R4 lesson: agg needs a huge grid + deep MLP, not per-bucket LDS atomics.
// R5 lesson: s_barrier is workgroup-scope; 64-wide scan in wave 0 uses shfl.
// R6 lesson: agg is gather-bytes-bound (150 MB L2-miss) -> bf16 rows halve it.

#define NB_MAX 1024  // max buckets (n <= 65536 for ushort src packing)

__device__ inline unsigned short f2bf(float f) {      // RNE fp32 -> bf16
    unsigned u = __builtin_bit_cast(unsigned, f);
    return (unsigned short)((u + 0x7FFFu + ((u >> 16) & 1u)) >> 16);
}
__device__ inline float bf2f(unsigned short b) {
    return __builtin_bit_cast(float, (unsigned)b << 16);
}

// ---- 1. per-block bucket histogram ----------------------------------------

__global__ __launch_bounds__(256) void k_hist(const int* __restrict__ ei, int E,
                                              int nb, int chunk,
                                              int* __restrict__ histT) {
    __shared__ int h[NB_MAX];
    for (int i = threadIdx.x; i < nb; i += 256) h[i] = 0;
    __syncthreads();
    int e0 = blockIdx.x * chunk, e1 = min(E, e0 + chunk);
    for (int e = e0 + threadIdx.x; e < e1; e += 256)
        atomicAdd(&h[ei[E + e] >> 6], 1);          // LDS atomic
    __syncthreads();
    for (int b = threadIdx.x; b < nb; b += 256)
        histT[b * 256 + blockIdx.x] = h[b];        // [bucket][block]
}

// ---- 2. scan each bucket's 256 per-block counts ---------------------------

__global__ __launch_bounds__(256) void k_scan_cols(int* __restrict__ histT,
                                                   int* __restrict__ total) {
    __shared__ int sm[256];
    int b = blockIdx.x, t = threadIdx.x;
    int v = histT[b * 256 + t];
    sm[t] = v;
    __syncthreads();
    for (int off = 1; off < 256; off <<= 1) {
        int u = (t >= off) ? sm[t - off] : 0;
        __syncthreads();
        sm[t] += u;
        __syncthreads();
    }
    histT[b * 256 + t] = sm[t] - v;                // exclusive within bucket
    if (t == 255) total[b] = sm[255];
}

// ---- 3. scan bucket totals -> bucket bases --------------------------------

__global__ __launch_bounds__(1024) void k_scan_totals(const int* __restrict__ total,
                                                      int* __restrict__ base, int nb) {
    __shared__ int sm[1024];
    int t = threadIdx.x;
    int v = (t < nb) ? total[t] : 0;
    sm[t] = v;
    __syncthreads();
    for (int off = 1; off < 1024; off <<= 1) {
        int u = (t >= off) ? sm[t - off] : 0;
        __syncthreads();
        sm[t] += u;
        __syncthreads();
    }
    if (t < nb) base[t] = sm[t] - v;               // exclusive
    if (t == nb - 1) base[nb] = sm[t];             // total E
}

// ---- 4. scatter packed edges into bucket-grouped order --------------------

__global__ __launch_bounds__(256) void k_scatter(const int* __restrict__ ei, int E,
                                                 int nb, int chunk,
                                                 const int* __restrict__ histT,
                                                 const int* __restrict__ base,
                                                 unsigned* __restrict__ packed) {
    __shared__ int cur[NB_MAX];
    for (int b = threadIdx.x; b < nb; b += 256)
        cur[b] = base[b] + histT[b * 256 + blockIdx.x];
    __syncthreads();
    int e0 = blockIdx.x * chunk, e1 = min(E, e0 + chunk);
    for (int e = e0 + threadIdx.x; e < e1; e += 256) {
        int s = ei[e], d = ei[E + e];
        int pos = atomicAdd(&cur[d >> 6], 1);      // LDS atomic
        packed[pos] = (unsigned)s | ((unsigned)(d & 63) << 16);
    }
}

// ---- 5. per-bucket CSR: offs, dinv, node-ordered ushort src list ----------

__global__ __launch_bounds__(256) void k_csr(const unsigned* __restrict__ packed,
                                             const int* __restrict__ base, int n,
                                             int* __restrict__ offs,
                                             float* __restrict__ dinv,
                                             unsigned short* __restrict__ ssrc) {
    __shared__ int cnt[64];
    __shared__ int cur[64];
    const int b = blockIdx.x, t = threadIdx.x;
    const int p0 = base[b], p1 = base[b + 1];
    if (t < 64) cnt[t] = 0;
    __syncthreads();
    for (int p = p0 + t; p < p1; p += 256)
        atomicAdd(&cnt[(packed[p] >> 16) & 63], 1);
    __syncthreads();
    if (t < 64) {                      // threads 0..63 == wave 0: shuffle scan
        int s = cnt[t];
        int sum = s;
#pragma unroll
        for (int d = 1; d < 64; d <<= 1) {
            int u = __shfl_up(sum, d, 64);
            if (t >= d) sum += u;
        }
        int excl = sum - s;            // exclusive scan
        int node = (b << 6) + t;
        if (node < n) {
            offs[node] = p0 + excl;
            dinv[node] = 1.0f / sqrtf((float)(s + 1));  // +1 self-loop
        }
        cur[t] = p0 + excl;
    }
    if (b == 0 && t == 0) offs[n] = base[(n + 63) >> 6];  // = E
    __syncthreads();
    for (int p = p0 + t; p < p1; p += 256) {
        unsigned k = packed[p];
        int pos = atomicAdd(&cur[(k >> 16) & 63], 1);
        ssrc[pos] = (unsigned short)(k & 0xFFFFu); // ~4 KB window scatter
    }
}

// ---- GEMM: HS[n,64] = bf16( dinv[:,None] * (X[n,K] @ W[K,64]) ) ------------
// Register-tiled: block(256) = 64x64 tile; thread = 4x4. dinv pre-scale fused.

#define FMA4(A, s, wv)                                                         \
    (A).x += (s) * (wv).x; (A).y += (s) * (wv).y;                              \
    (A).z += (s) * (wv).z; (A).w += (s) * (wv).w;

template <int K>
__global__ __launch_bounds__(256) void k_gemm(const float* __restrict__ X,
                                              const float* __restrict__ W,
                                              const float* __restrict__ dinv,
                                              unsigned short* __restrict__ HS,
                                              int n) {
    __shared__ float xl[64][36];
    __shared__ float wl[32][64];

    const int t = threadIdx.x;
    const int tc = t & 15;
    const int tr = t >> 4;
    const int row0 = blockIdx.x * 64;

    float4 acc[4];
    acc[0] = acc[1] = acc[2] = acc[3] = make_float4(0.f, 0.f, 0.f, 0.f);

    for (int k0 = 0; k0 < K; k0 += 32) {
#pragma unroll
        for (int i = 0; i < 2; ++i) {
            int idx = i * 256 + t;
            int r = idx >> 3, f4 = idx & 7;
            int gr = row0 + r;
            float4 v = make_float4(0.f, 0.f, 0.f, 0.f);
            if (gr < n) v = *(const float4*)(X + (size_t)gr * K + k0 + f4 * 4);
            *(float4*)&xl[r][f4 * 4] = v;
        }
#pragma unroll
        for (int i = 0; i < 2; ++i) {
            int idx = i * 256 + t;
            int kr = idx >> 4, f4 = idx & 15;
            *(float4*)&wl[kr][f4 * 4] =
                *(const float4*)(W + (size_t)(k0 + kr) * 64 + f4 * 4);
        }
        __syncthreads();

#pragma unroll
        for (int kk = 0; kk < 32; kk += 4) {
            float4 xv0 = *(float4*)&xl[tr * 4 + 0][kk];
            float4 xv1 = *(float4*)&xl[tr * 4 + 1][kk];
            float4 xv2 = *(float4*)&xl[tr * 4 + 2][kk];
            float4 xv3 = *(float4*)&xl[tr * 4 + 3][kk];
            float4 wv0 = *(float4*)&wl[kk + 0][tc * 4];
            float4 wv1 = *(float4*)&wl[kk + 1][tc * 4];
            float4 wv2 = *(float4*)&wl[kk + 2][tc * 4];
            float4 wv3 = *(float4*)&wl[kk + 3][tc * 4];

            FMA4(acc[0], xv0.x, wv0); FMA4(acc[0], xv0.y, wv1);
            FMA4(acc[0], xv0.z, wv2); FMA4(acc[0], xv0.w, wv3);
            FMA4(acc[1], xv1.x, wv0); FMA4(acc[1], xv1.y, wv1);
            FMA4(acc[1], xv1.z, wv2); FMA4(acc[1], xv1.w, wv3);
            FMA4(acc[2], xv2.x, wv0); FMA4(acc[2], xv2.y, wv1);
            FMA4(acc[2], xv2.z, wv2); FMA4(acc[2], xv2.w, wv3);
            FMA4(acc[3], xv3.x, wv0); FMA4(acc[3], xv3.y, wv1);
            FMA4(acc[3], xv3.z, wv2); FMA4(acc[3], xv3.w, wv3);
        }
        __syncthreads();
    }

#pragma unroll
    for (int ri = 0; ri < 4; ++ri) {
        int gr = row0 + tr * 4 + ri;
        if (gr < n) {
            float dv = dinv[gr];
            float4 o = acc[ri];
            ushort4 pk;
            pk.x = f2bf(o.x * dv); pk.y = f2bf(o.y * dv);
            pk.z = f2bf(o.z * dv); pk.w = f2bf(o.w * dv);
            *(ushort4*)(HS + (size_t)gr * 64 + tc * 4) = pk;
        }
    }
}

// ---- 6. aggregation: out[i] = dinv[i]*(sum_src hs[src] + hs[i]) + b -------
// Wave per node, lane = channel. 8 bf16 gathers (128B rows) in flight.
// ssrc/offs reads are wave-uniform -> scalar loads. fp32 accumulation.

template <bool RELU>
__global__ void k_agg(const unsigned short* __restrict__ hs,
                      const int* __restrict__ offs,
                      const unsigned short* __restrict__ ssrc,
                      const float* __restrict__ dinv,
                      const float* __restrict__ bias,
                      float* __restrict__ out, int n) {
    int node = blockIdx.x * 4 + (threadIdx.x >> 6);
    if (node >= n) return;
    int lane = threadIdx.x & 63;

    int beg = offs[node];
    int end = offs[node + 1];
    float acc = bf2f(hs[(size_t)node * 64 + lane]);   // self-loop (pre-scaled)

    int p = beg;
    for (; p + 7 < end; p += 8) {
        int s0 = ssrc[p + 0], s1 = ssrc[p + 1], s2 = ssrc[p + 2], s3 = ssrc[p + 3];
        int s4 = ssrc[p + 4], s5 = ssrc[p + 5], s6 = ssrc[p + 6], s7 = ssrc[p + 7];
        unsigned short u0 = hs[(size_t)s0 * 64 + lane];
        unsigned short u1 = hs[(size_t)s1 * 64 + lane];
        unsigned short u2 = hs[(size_t)s2 * 64 + lane];
        unsigned short u3 = hs[(size_t)s3 * 64 + lane];
        unsigned short u4 = hs[(size_t)s4 * 64 + lane];
        unsigned short u5 = hs[(size_t)s5 * 64 + lane];
        unsigned short u6 = hs[(size_t)s6 * 64 + lane];
        unsigned short u7 = hs[(size_t)s7 * 64 + lane];
        acc += ((bf2f(u0) + bf2f(u1)) + (bf2f(u2) + bf2f(u3))) +
               ((bf2f(u4) + bf2f(u5)) + (bf2f(u6) + bf2f(u7)));
    }
    for (; p < end; ++p)
        acc += bf2f(hs[(size_t)ssrc[p] * 64 + lane]);

    float r = dinv[node] * acc + bias[lane];
    if (RELU) r = fmaxf(r, 0.0f);
    out[(size_t)node * 64 + lane] = r;
}

// ---- launch ----------------------------------------------------------------

extern "C" void kernel_launch(void* const* d_in, const int* in_sizes, int n_in,
                              void* d_out, int out_size, void* d_ws, size_t ws_size,
                              hipStream_t stream) {
    const float* x  = (const float*)d_in[0];
    const int*   ei = (const int*)d_in[1];
    const float* W1 = (const float*)d_in[2];
    const float* b1 = (const float*)d_in[3];
    const float* W2 = (const float*)d_in[4];
    const float* b2 = (const float*)d_in[5];

    const int n = in_sizes[0] / 256;   // 50000 (< 65536: ushort src packing)
    const int E = in_sizes[1] / 2;     // 1600000
    const int nb = (n + 63) >> 6;      // 782 buckets
    const int chunk = (E + 255) / 256;

    // workspace carve-up (256B aligned)
    char* ws = (char*)d_ws;
    auto carve = [&](size_t bytes) {
        void* p = (void*)ws;
        ws += (bytes + 255) & ~(size_t)255;
        return p;
    };
    int*            histT  = (int*)carve((size_t)nb * 256 * 4);
    int*            total  = (int*)carve((size_t)nb * 4);
    int*            base   = (int*)carve((size_t)(nb + 1) * 4);
    unsigned*       packed = (unsigned*)carve((size_t)E * 4);
    unsigned short* ssrc   = (unsigned short*)carve((size_t)E * 2);
    int*            offs   = (int*)carve((size_t)(n + 1) * 4);
    float*          dinv   = (float*)carve((size_t)n * 4);
    unsigned short* hs1    = (unsigned short*)carve((size_t)n * 64 * 2);
    float*          hB     = (float*)carve((size_t)n * 64 * 4);
    unsigned short* hs2    = (unsigned short*)carve((size_t)n * 64 * 2);

    k_hist<<<256, 256, 0, stream>>>(ei, E, nb, chunk, histT);
    k_scan_cols<<<nb, 256, 0, stream>>>(histT, total);
    k_scan_totals<<<1, 1024, 0, stream>>>(total, base, nb);
    k_scatter<<<256, 256, 0, stream>>>(ei, E, nb, chunk, histT, base, packed);
    k_csr<<<nb, 256, 0, stream>>>(packed, base, n, offs, dinv, ssrc);

    const int nbG = (n + 63) / 64;

    // layer 1: hs1 = bf16(dinv*(x@W1)) ; hB = relu(agg + b1)
    k_gemm<256><<<nbG, 256, 0, stream>>>(x, W1, dinv, hs1, n);
    k_agg<true><<<(n + 3) / 4, 256, 0, stream>>>(hs1, offs, ssrc, dinv, b1, hB, n);

    // layer 2: hs2 = bf16(dinv*(hB@W2)) ; out = agg + b2
    k_gemm<64><<<nbG, 256, 0, stream>>>(hB, W2, dinv, hs2, n);
    k_agg<false><<<(n + 3) / 4, 256, 0, stream>>>(hs2, offs, ssrc, dinv, b2,
                                                  (float*)d_out, n);
}

// Round 8
// 255.717 us; speedup vs baseline: 5.9764x; 1.0310x over previous
//
#include <hip/hip_runtime.h>
#include <hip/hip_bf16.h>

// GCN 2-layer: h1 = relu(Ahat @ (x@W1) + b1); out = Ahat @ (h1@W2) + b2
// Ahat = D^-1/2 (A + I) D^-1/2.
//
// Pipeline (zero global atomics):
//   k_hist/k_scan_cols/k_scan_totals/k_scatter: deterministic bucket partition
//     (bucket = dst>>6, 782 buckets) via per-block LDS histograms.
//   k_csr: per bucket -> per-node offsets (offs), dinv, node-ordered ushort src.
//   k_gemm: register-tiled 64x64; epilogue writes hs = bf16(dinv * (X@W)).
//   k_agg: wave per node; DUAL-EDGE gathers: lanes 0-31 = edge A (uint = 2
//     bf16 ch), lanes 32-63 = edge B -> 2 edges per VMEM instr, 16 edges in
//     flight; shfl_xor(32) reduce; fp32 accumulate. No atomics.
// R3 lesson: never funnel E atomics into few global addresses.
// R4 lesson: agg needs a huge grid + deep MLP, not per-bucket LDS atomics.
// R5 lesson: s_barrier is workgroup-scope; 64-wide scan in wave 0 uses shfl.
// R6 lesson: bf16 rows halve gather bytes.
// R7 lesson: agg is VMEM-issue/latency bound, not bytes bound -> pack 2 edges
//   per gather instruction and broadcast-load src pairs.

#define NB_MAX 1024  // max buckets (n <= 65536 for ushort src packing)

__device__ inline unsigned short f2bf(float f) {      // RNE fp32 -> bf16
    unsigned u = __builtin_bit_cast(unsigned, f);
    return (unsigned short)((u + 0x7FFFu + ((u >> 16) & 1u)) >> 16);
}
__device__ inline float bf2f(unsigned short b) {
    return __builtin_bit_cast(float, (unsigned)b << 16);
}

// ---- 1. per-block bucket histogram ----------------------------------------

__global__ __launch_bounds__(256) void k_hist(const int* __restrict__ ei, int E,
                                              int nb, int chunk,
                                              int* __restrict__ histT) {
    __shared__ int h[NB_MAX];
    for (int i = threadIdx.x; i < nb; i += 256) h[i] = 0;
    __syncthreads();
    int e0 = blockIdx.x * chunk, e1 = min(E, e0 + chunk);
    for (int e = e0 + threadIdx.x; e < e1; e += 256)
        atomicAdd(&h[ei[E + e] >> 6], 1);          // LDS atomic
    __syncthreads();
    for (int b = threadIdx.x; b < nb; b += 256)
        histT[b * 256 + blockIdx.x] = h[b];        // [bucket][block]
}

// ---- 2. scan each bucket's 256 per-block counts ---------------------------

__global__ __launch_bounds__(256) void k_scan_cols(int* __restrict__ histT,
                                                   int* __restrict__ total) {
    __shared__ int sm[256];
    int b = blockIdx.x, t = threadIdx.x;
    int v = histT[b * 256 + t];
    sm[t] = v;
    __syncthreads();
    for (int off = 1; off < 256; off <<= 1) {
        int u = (t >= off) ? sm[t - off] : 0;
        __syncthreads();
        sm[t] += u;
        __syncthreads();
    }
    histT[b * 256 + t] = sm[t] - v;                // exclusive within bucket
    if (t == 255) total[b] = sm[255];
}

// ---- 3. scan bucket totals -> bucket bases --------------------------------

__global__ __launch_bounds__(1024) void k_scan_totals(const int* __restrict__ total,
                                                      int* __restrict__ base, int nb) {
    __shared__ int sm[1024];
    int t = threadIdx.x;
    int v = (t < nb) ? total[t] : 0;
    sm[t] = v;
    __syncthreads();
    for (int off = 1; off < 1024; off <<= 1) {
        int u = (t >= off) ? sm[t - off] : 0;
        __syncthreads();
        sm[t] += u;
        __syncthreads();
    }
    if (t < nb) base[t] = sm[t] - v;               // exclusive
    if (t == nb - 1) base[nb] = sm[t];             // total E
}

// ---- 4. scatter packed edges into bucket-grouped order --------------------

__global__ __launch_bounds__(256) void k_scatter(const int* __restrict__ ei, int E,
                                                 int nb, int chunk,
                                                 const int* __restrict__ histT,
                                                 const int* __restrict__ base,
                                                 unsigned* __restrict__ packed) {
    __shared__ int cur[NB_MAX];
    for (int b = threadIdx.x; b < nb; b += 256)
        cur[b] = base[b] + histT[b * 256 + blockIdx.x];
    __syncthreads();
    int e0 = blockIdx.x * chunk, e1 = min(E, e0 + chunk);
    for (int e = e0 + threadIdx.x; e < e1; e += 256) {
        int s = ei[e], d = ei[E + e];
        int pos = atomicAdd(&cur[d >> 6], 1);      // LDS atomic
        packed[pos] = (unsigned)s | ((unsigned)(d & 63) << 16);
    }
}

// ---- 5. per-bucket CSR: offs, dinv, node-ordered ushort src list ----------

__global__ __launch_bounds__(256) void k_csr(const unsigned* __restrict__ packed,
                                             const int* __restrict__ base, int n,
                                             int* __restrict__ offs,
                                             float* __restrict__ dinv,
                                             unsigned short* __restrict__ ssrc) {
    __shared__ int cnt[64];
    __shared__ int cur[64];
    const int b = blockIdx.x, t = threadIdx.x;
    const int p0 = base[b], p1 = base[b + 1];
    if (t < 64) cnt[t] = 0;
    __syncthreads();
    for (int p = p0 + t; p < p1; p += 256)
        atomicAdd(&cnt[(packed[p] >> 16) & 63], 1);
    __syncthreads();
    if (t < 64) {                      // threads 0..63 == wave 0: shuffle scan
        int s = cnt[t];
        int sum = s;
#pragma unroll
        for (int d = 1; d < 64; d <<= 1) {
            int u = __shfl_up(sum, d, 64);
            if (t >= d) sum += u;
        }
        int excl = sum - s;            // exclusive scan
        int node = (b << 6) + t;
        if (node < n) {
            offs[node] = p0 + excl;
            dinv[node] = 1.0f / sqrtf((float)(s + 1));  // +1 self-loop
        }
        cur[t] = p0 + excl;
    }
    if (b == 0 && t == 0) offs[n] = base[(n + 63) >> 6];  // = E
    __syncthreads();
    for (int p = p0 + t; p < p1; p += 256) {
        unsigned k = packed[p];
        int pos = atomicAdd(&cur[(k >> 16) & 63], 1);
        ssrc[pos] = (unsigned short)(k & 0xFFFFu); // ~4 KB window scatter
    }
}

// ---- GEMM: HS[n,64] = bf16( dinv[:,None] * (X[n,K] @ W[K,64]) ) ------------
// Register-tiled: block(256) = 64x64 tile; thread = 4x4. dinv pre-scale fused.

#define FMA4(A, s, wv)                                                         \
    (A).x += (s) * (wv).x; (A).y += (s) * (wv).y;                              \
    (A).z += (s) * (wv).z; (A).w += (s) * (wv).w;

template <int K>
__global__ __launch_bounds__(256) void k_gemm(const float* __restrict__ X,
                                              const float* __restrict__ W,
                                              const float* __restrict__ dinv,
                                              unsigned short* __restrict__ HS,
                                              int n) {
    __shared__ float xl[64][36];
    __shared__ float wl[32][64];

    const int t = threadIdx.x;
    const int tc = t & 15;
    const int tr = t >> 4;
    const int row0 = blockIdx.x * 64;

    float4 acc[4];
    acc[0] = acc[1] = acc[2] = acc[3] = make_float4(0.f, 0.f, 0.f, 0.f);

    for (int k0 = 0; k0 < K; k0 += 32) {
#pragma unroll
        for (int i = 0; i < 2; ++i) {
            int idx = i * 256 + t;
            int r = idx >> 3, f4 = idx & 7;
            int gr = row0 + r;
            float4 v = make_float4(0.f, 0.f, 0.f, 0.f);
            if (gr < n) v = *(const float4*)(X + (size_t)gr * K + k0 + f4 * 4);
            *(float4*)&xl[r][f4 * 4] = v;
        }
#pragma unroll
        for (int i = 0; i < 2; ++i) {
            int idx = i * 256 + t;
            int kr = idx >> 4, f4 = idx & 15;
            *(float4*)&wl[kr][f4 * 4] =
                *(const float4*)(W + (size_t)(k0 + kr) * 64 + f4 * 4);
        }
        __syncthreads();

#pragma unroll
        for (int kk = 0; kk < 32; kk += 4) {
            float4 xv0 = *(float4*)&xl[tr * 4 + 0][kk];
            float4 xv1 = *(float4*)&xl[tr * 4 + 1][kk];
            float4 xv2 = *(float4*)&xl[tr * 4 + 2][kk];
            float4 xv3 = *(float4*)&xl[tr * 4 + 3][kk];
            float4 wv0 = *(float4*)&wl[kk + 0][tc * 4];
            float4 wv1 = *(float4*)&wl[kk + 1][tc * 4];
            float4 wv2 = *(float4*)&wl[kk + 2][tc * 4];
            float4 wv3 = *(float4*)&wl[kk + 3][tc * 4];

            FMA4(acc[0], xv0.x, wv0); FMA4(acc[0], xv0.y, wv1);
            FMA4(acc[0], xv0.z, wv2); FMA4(acc[0], xv0.w, wv3);
            FMA4(acc[1], xv1.x, wv0); FMA4(acc[1], xv1.y, wv1);
            FMA4(acc[1], xv1.z, wv2); FMA4(acc[1], xv1.w, wv3);
            FMA4(acc[2], xv2.x, wv0); FMA4(acc[2], xv2.y, wv1);
            FMA4(acc[2], xv2.z, wv2); FMA4(acc[2], xv2.w, wv3);
            FMA4(acc[3], xv3.x, wv0); FMA4(acc[3], xv3.y, wv1);
            FMA4(acc[3], xv3.z, wv2); FMA4(acc[3], xv3.w, wv3);
        }
        __syncthreads();
    }

#pragma unroll
    for (int ri = 0; ri < 4; ++ri) {
        int gr = row0 + tr * 4 + ri;
        if (gr < n) {
            float dv = dinv[gr];
            float4 o = acc[ri];
            ushort4 pk;
            pk.x = f2bf(o.x * dv); pk.y = f2bf(o.y * dv);
            pk.z = f2bf(o.z * dv); pk.w = f2bf(o.w * dv);
            *(ushort4*)(HS + (size_t)gr * 64 + tc * 4) = pk;
        }
    }
}

// ---- 6. aggregation: out[i] = dinv[i]*(sum_src hs[src] + hs[i]) + b -------
// Wave per node. Dual-edge gathers: lane = (half, cp); half selects edge,
// cp = channel pair (uint = 2 bf16). 8 dual gathers = 16 edges in flight.
// Head/tail peel keeps the src-pair index loads uint-aligned & wave-uniform.

template <bool RELU>
__global__ void k_agg(const unsigned short* __restrict__ hs,
                      const int* __restrict__ offs,
                      const unsigned short* __restrict__ ssrc,
                      const float* __restrict__ dinv,
                      const float* __restrict__ bias,
                      float* __restrict__ out, int n) {
    int node = blockIdx.x * 4 + (threadIdx.x >> 6);
    if (node >= n) return;
    const int lane = threadIdx.x & 63;
    const int half = lane >> 5;       // which edge of the pair
    const int cp   = lane & 31;       // channel pair: ch 2cp, 2cp+1

    const unsigned* hsu = (const unsigned*)hs;     // row = 32 uints (128 B)
    const unsigned* ssu = (const unsigned*)ssrc;   // src pairs

    int p = offs[node];
    const int end = offs[node + 1];
    float2 acc = make_float2(0.f, 0.f);

    // head peel: make p even so pair loads are 4B-aligned
    if ((p & 1) && p < end) {
        unsigned v = hsu[(int)ssrc[p] * 32 + cp];
        if (half == 0) {
            acc.x += bf2f((unsigned short)(v & 0xFFFFu));
            acc.y += bf2f((unsigned short)(v >> 16));
        }
        ++p;
    }

    // 16 edges per iter: 8 uniform pair-index loads + 8 dual gathers
    for (; p + 15 < end; p += 16) {
        unsigned ss[8];
#pragma unroll
        for (int j = 0; j < 8; ++j) ss[j] = ssu[(p >> 1) + j];
        unsigned v[8];
#pragma unroll
        for (int j = 0; j < 8; ++j) {
            int s = half ? (int)(ss[j] >> 16) : (int)(ss[j] & 0xFFFFu);
            v[j] = hsu[s * 32 + cp];
        }
#pragma unroll
        for (int j = 0; j < 8; ++j) {
            acc.x += bf2f((unsigned short)(v[j] & 0xFFFFu));
            acc.y += bf2f((unsigned short)(v[j] >> 16));
        }
    }
    // remaining pairs
    for (; p + 1 < end; p += 2) {
        unsigned ss = ssu[p >> 1];
        int s = half ? (int)(ss >> 16) : (int)(ss & 0xFFFFu);
        unsigned v = hsu[s * 32 + cp];
        acc.x += bf2f((unsigned short)(v & 0xFFFFu));
        acc.y += bf2f((unsigned short)(v >> 16));
    }
    // tail single edge
    if (p < end) {
        unsigned v = hsu[(int)ssrc[p] * 32 + cp];
        if (half == 0) {
            acc.x += bf2f((unsigned short)(v & 0xFFFFu));
            acc.y += bf2f((unsigned short)(v >> 16));
        }
    }

    // combine the two halves
    acc.x += __shfl_xor(acc.x, 32, 64);
    acc.y += __shfl_xor(acc.y, 32, 64);

    // epilogue on lanes 0..31: self-loop + scale + bias (+ relu)
    unsigned sv = hsu[node * 32 + cp];
    float dv = dinv[node];
    float2 bv = *(const float2*)(bias + 2 * cp);
    float rx = dv * (acc.x + bf2f((unsigned short)(sv & 0xFFFFu))) + bv.x;
    float ry = dv * (acc.y + bf2f((unsigned short)(sv >> 16))) + bv.y;
    if (RELU) { rx = fmaxf(rx, 0.f); ry = fmaxf(ry, 0.f); }
    if (half == 0)
        *(float2*)(out + (size_t)node * 64 + 2 * cp) = make_float2(rx, ry);
}

// ---- launch ----------------------------------------------------------------

extern "C" void kernel_launch(void* const* d_in, const int* in_sizes, int n_in,
                              void* d_out, int out_size, void* d_ws, size_t ws_size,
                              hipStream_t stream) {
    const float* x  = (const float*)d_in[0];
    const int*   ei = (const int*)d_in[1];
    const float* W1 = (const float*)d_in[2];
    const float* b1 = (const float*)d_in[3];
    const float* W2 = (const float*)d_in[4];
    const float* b2 = (const float*)d_in[5];

    const int n = in_sizes[0] / 256;   // 50000 (< 65536: ushort src packing)
    const int E = in_sizes[1] / 2;     // 1600000
    const int nb = (n + 63) >> 6;      // 782 buckets
    const int chunk = (E + 255) / 256;

    // workspace carve-up (256B aligned)
    char* ws = (char*)d_ws;
    auto carve = [&](size_t bytes) {
        void* p = (void*)ws;
        ws += (bytes + 255) & ~(size_t)255;
        return p;
    };
    int*            histT  = (int*)carve((size_t)nb * 256 * 4);
    int*            total  = (int*)carve((size_t)nb * 4);
    int*            base   = (int*)carve((size_t)(nb + 1) * 4);
    unsigned*       packed = (unsigned*)carve((size_t)E * 4);
    unsigned short* ssrc   = (unsigned short*)carve((size_t)E * 2);
    int*            offs   = (int*)carve((size_t)(n + 1) * 4);
    float*          dinv   = (float*)carve((size_t)n * 4);
    unsigned short* hs1    = (unsigned short*)carve((size_t)n * 64 * 2);
    float*          hB     = (float*)carve((size_t)n * 64 * 4);
    unsigned short* hs2    = (unsigned short*)carve((size_t)n * 64 * 2);

    k_hist<<<256, 256, 0, stream>>>(ei, E, nb, chunk, histT);
    k_scan_cols<<<nb, 256, 0, stream>>>(histT, total);
    k_scan_totals<<<1, 1024, 0, stream>>>(total, base, nb);
    k_scatter<<<256, 256, 0, stream>>>(ei, E, nb, chunk, histT, base, packed);
    k_csr<<<nb, 256, 0, stream>>>(packed, base, n, offs, dinv, ssrc);

    const int nbG = (n + 63) / 64;

    // layer 1: hs1 = bf16(dinv*(x@W1)) ; hB = relu(agg + b1)
    k_gemm<256><<<nbG, 256, 0, stream>>>(x, W1, dinv, hs1, n);
    k_agg<true><<<(n + 3) / 4, 256, 0, stream>>>(hs1, offs, ssrc, dinv, b1, hB, n);

    // layer 2: hs2 = bf16(dinv*(hB@W2)) ; out = agg + b2
    k_gemm<64><<<nbG, 256, 0, stream>>>(hB, W2, dinv, hs2, n);
    k_agg<false><<<(n + 3) / 4, 256, 0, stream>>>(hs2, offs, ssrc, dinv, b2,
                                                  (float*)d_out, n);
}

// Round 9
// 240.390 us; speedup vs baseline: 6.3574x; 1.0638x over previous
//
#include <hip/hip_runtime.h>
#include <hip/hip_bf16.h>

// GCN 2-layer: h1 = relu(Ahat @ (x@W1) + b1); out = Ahat @ (h1@W2) + b2
// Ahat = D^-1/2 (A + I) D^-1/2.
//
// Pipeline (zero global atomics):
//   k_hist/k_scan_cols/k_scan_totals/k_scatter: deterministic bucket partition
//     (bucket = dst>>6, 782 buckets) via per-block LDS histograms.
//   k_csr: per bucket -> per-node offsets (offs), dinv, node-ordered ushort src.
//   k_gemm: register-tiled 64x64; epilogue writes hs = bf16(dinv * (X@W)).
//   k_agg: wave per node; dual-edge gathers (lanes 0-31 = lo edge, 32-63 = hi
//     edge of a src pair); PREDICATED 16-pair batches -> 16 gathers in flight,
//     no head-peel/remainder serialization; scalar (s_load) pair indices.
// R3 lesson: never funnel E atomics into few global addresses.
// R4 lesson: agg needs a huge grid + deep MLP, not per-bucket LDS atomics.
// R5 lesson: s_barrier is workgroup-scope; 64-wide scan in wave 0 uses shfl.
// R6 lesson: bf16 rows halve gather bytes.
// R7 lesson: agg is VMEM-issue/latency bound -> 2 edges per gather instr.
// R8 lesson: the scalar remainder loop dominated latency (deg%32 edges with 1
//   gather in flight); replace with masked full-width batches.

#define NB_MAX 1024  // max buckets (n <= 65536 for ushort src packing)

__device__ inline unsigned short f2bf(float f) {      // RNE fp32 -> bf16
    unsigned u = __builtin_bit_cast(unsigned, f);
    return (unsigned short)((u + 0x7FFFu + ((u >> 16) & 1u)) >> 16);
}
__device__ inline float bf2f(unsigned short b) {
    return __builtin_bit_cast(float, (unsigned)b << 16);
}

// ---- 1. per-block bucket histogram ----------------------------------------

__global__ __launch_bounds__(256) void k_hist(const int* __restrict__ ei, int E,
                                              int nb, int chunk,
                                              int* __restrict__ histT) {
    __shared__ int h[NB_MAX];
    for (int i = threadIdx.x; i < nb; i += 256) h[i] = 0;
    __syncthreads();
    int e0 = blockIdx.x * chunk, e1 = min(E, e0 + chunk);
    for (int e = e0 + threadIdx.x; e < e1; e += 256)
        atomicAdd(&h[ei[E + e] >> 6], 1);          // LDS atomic
    __syncthreads();
    for (int b = threadIdx.x; b < nb; b += 256)
        histT[b * 256 + blockIdx.x] = h[b];        // [bucket][block]
}

// ---- 2. scan each bucket's 256 per-block counts ---------------------------

__global__ __launch_bounds__(256) void k_scan_cols(int* __restrict__ histT,
                                                   int* __restrict__ total) {
    __shared__ int sm[256];
    int b = blockIdx.x, t = threadIdx.x;
    int v = histT[b * 256 + t];
    sm[t] = v;
    __syncthreads();
    for (int off = 1; off < 256; off <<= 1) {
        int u = (t >= off) ? sm[t - off] : 0;
        __syncthreads();
        sm[t] += u;
        __syncthreads();
    }
    histT[b * 256 + t] = sm[t] - v;                // exclusive within bucket
    if (t == 255) total[b] = sm[255];
}

// ---- 3. scan bucket totals -> bucket bases --------------------------------

__global__ __launch_bounds__(1024) void k_scan_totals(const int* __restrict__ total,
                                                      int* __restrict__ base, int nb) {
    __shared__ int sm[1024];
    int t = threadIdx.x;
    int v = (t < nb) ? total[t] : 0;
    sm[t] = v;
    __syncthreads();
    for (int off = 1; off < 1024; off <<= 1) {
        int u = (t >= off) ? sm[t - off] : 0;
        __syncthreads();
        sm[t] += u;
        __syncthreads();
    }
    if (t < nb) base[t] = sm[t] - v;               // exclusive
    if (t == nb - 1) base[nb] = sm[t];             // total E
}

// ---- 4. scatter packed edges into bucket-grouped order --------------------

__global__ __launch_bounds__(256) void k_scatter(const int* __restrict__ ei, int E,
                                                 int nb, int chunk,
                                                 const int* __restrict__ histT,
                                                 const int* __restrict__ base,
                                                 unsigned* __restrict__ packed) {
    __shared__ int cur[NB_MAX];
    for (int b = threadIdx.x; b < nb; b += 256)
        cur[b] = base[b] + histT[b * 256 + blockIdx.x];
    __syncthreads();
    int e0 = blockIdx.x * chunk, e1 = min(E, e0 + chunk);
    for (int e = e0 + threadIdx.x; e < e1; e += 256) {
        int s = ei[e], d = ei[E + e];
        int pos = atomicAdd(&cur[d >> 6], 1);      // LDS atomic
        packed[pos] = (unsigned)s | ((unsigned)(d & 63) << 16);
    }
}

// ---- 5. per-bucket CSR: offs, dinv, node-ordered ushort src list ----------

__global__ __launch_bounds__(256) void k_csr(const unsigned* __restrict__ packed,
                                             const int* __restrict__ base, int n,
                                             int* __restrict__ offs,
                                             float* __restrict__ dinv,
                                             unsigned short* __restrict__ ssrc) {
    __shared__ int cnt[64];
    __shared__ int cur[64];
    const int b = blockIdx.x, t = threadIdx.x;
    const int p0 = base[b], p1 = base[b + 1];
    if (t < 64) cnt[t] = 0;
    __syncthreads();
    for (int p = p0 + t; p < p1; p += 256)
        atomicAdd(&cnt[(packed[p] >> 16) & 63], 1);
    __syncthreads();
    if (t < 64) {                      // threads 0..63 == wave 0: shuffle scan
        int s = cnt[t];
        int sum = s;
#pragma unroll
        for (int d = 1; d < 64; d <<= 1) {
            int u = __shfl_up(sum, d, 64);
            if (t >= d) sum += u;
        }
        int excl = sum - s;            // exclusive scan
        int node = (b << 6) + t;
        if (node < n) {
            offs[node] = p0 + excl;
            dinv[node] = 1.0f / sqrtf((float)(s + 1));  // +1 self-loop
        }
        cur[t] = p0 + excl;
    }
    if (b == 0 && t == 0) offs[n] = base[(n + 63) >> 6];  // = E
    __syncthreads();
    for (int p = p0 + t; p < p1; p += 256) {
        unsigned k = packed[p];
        int pos = atomicAdd(&cur[(k >> 16) & 63], 1);
        ssrc[pos] = (unsigned short)(k & 0xFFFFu); // ~4 KB window scatter
    }
}

// ---- GEMM: HS[n,64] = bf16( dinv[:,None] * (X[n,K] @ W[K,64]) ) ------------
// Register-tiled: block(256) = 64x64 tile; thread = 4x4. dinv pre-scale fused.

#define FMA4(A, s, wv)                                                         \
    (A).x += (s) * (wv).x; (A).y += (s) * (wv).y;                              \
    (A).z += (s) * (wv).z; (A).w += (s) * (wv).w;

template <int K>
__global__ __launch_bounds__(256) void k_gemm(const float* __restrict__ X,
                                              const float* __restrict__ W,
                                              const float* __restrict__ dinv,
                                              unsigned short* __restrict__ HS,
                                              int n) {
    __shared__ float xl[64][36];
    __shared__ float wl[32][64];

    const int t = threadIdx.x;
    const int tc = t & 15;
    const int tr = t >> 4;
    const int row0 = blockIdx.x * 64;

    float4 acc[4];
    acc[0] = acc[1] = acc[2] = acc[3] = make_float4(0.f, 0.f, 0.f, 0.f);

    for (int k0 = 0; k0 < K; k0 += 32) {
#pragma unroll
        for (int i = 0; i < 2; ++i) {
            int idx = i * 256 + t;
            int r = idx >> 3, f4 = idx & 7;
            int gr = row0 + r;
            float4 v = make_float4(0.f, 0.f, 0.f, 0.f);
            if (gr < n) v = *(const float4*)(X + (size_t)gr * K + k0 + f4 * 4);
            *(float4*)&xl[r][f4 * 4] = v;
        }
#pragma unroll
        for (int i = 0; i < 2; ++i) {
            int idx = i * 256 + t;
            int kr = idx >> 4, f4 = idx & 15;
            *(float4*)&wl[kr][f4 * 4] =
                *(const float4*)(W + (size_t)(k0 + kr) * 64 + f4 * 4);
        }
        __syncthreads();

#pragma unroll
        for (int kk = 0; kk < 32; kk += 4) {
            float4 xv0 = *(float4*)&xl[tr * 4 + 0][kk];
            float4 xv1 = *(float4*)&xl[tr * 4 + 1][kk];
            float4 xv2 = *(float4*)&xl[tr * 4 + 2][kk];
            float4 xv3 = *(float4*)&xl[tr * 4 + 3][kk];
            float4 wv0 = *(float4*)&wl[kk + 0][tc * 4];
            float4 wv1 = *(float4*)&wl[kk + 1][tc * 4];
            float4 wv2 = *(float4*)&wl[kk + 2][tc * 4];
            float4 wv3 = *(float4*)&wl[kk + 3][tc * 4];

            FMA4(acc[0], xv0.x, wv0); FMA4(acc[0], xv0.y, wv1);
            FMA4(acc[0], xv0.z, wv2); FMA4(acc[0], xv0.w, wv3);
            FMA4(acc[1], xv1.x, wv0); FMA4(acc[1], xv1.y, wv1);
            FMA4(acc[1], xv1.z, wv2); FMA4(acc[1], xv1.w, wv3);
            FMA4(acc[2], xv2.x, wv0); FMA4(acc[2], xv2.y, wv1);
            FMA4(acc[2], xv2.z, wv2); FMA4(acc[2], xv2.w, wv3);
            FMA4(acc[3], xv3.x, wv0); FMA4(acc[3], xv3.y, wv1);
            FMA4(acc[3], xv3.z, wv2); FMA4(acc[3], xv3.w, wv3);
        }
        __syncthreads();
    }

#pragma unroll
    for (int ri = 0; ri < 4; ++ri) {
        int gr = row0 + tr * 4 + ri;
        if (gr < n) {
            float dv = dinv[gr];
            float4 o = acc[ri];
            ushort4 pk;
            pk.x = f2bf(o.x * dv); pk.y = f2bf(o.y * dv);
            pk.z = f2bf(o.z * dv); pk.w = f2bf(o.w * dv);
            *(ushort4*)(HS + (size_t)gr * 64 + tc * 4) = pk;
        }
    }
}

// ---- 6. aggregation: out[i] = dinv[i]*(sum_src hs[src] + hs[i]) + b -------
// Wave per node. Dual-edge gathers: lane = (half, cp); half selects the lo/hi
// edge of a src pair, cp = channel pair (uint = 2 bf16). Predicated 16-pair
// batches: 16 gathers in flight, both list ends handled by masking (dead slots
// clamp to qmax -> one broadcast line). Pair indices are wave-uniform
// (readfirstlane) -> scalar loads off the VMEM pipe.

template <bool RELU>
__global__ void k_agg(const unsigned short* __restrict__ hs,
                      const int* __restrict__ offs,
                      const unsigned short* __restrict__ ssrc,
                      const float* __restrict__ dinv,
                      const float* __restrict__ bias,
                      float* __restrict__ out, int n, int qmax) {
    int node = blockIdx.x * 4 + (threadIdx.x >> 6);
    if (node >= n) return;
    node = __builtin_amdgcn_readfirstlane(node);   // force SGPR -> s_loads below
    const int lane = threadIdx.x & 63;
    const int half = lane >> 5;       // lo/hi edge of the pair
    const int cp   = lane & 31;       // channel pair: ch 2cp, 2cp+1

    const unsigned* hsu = (const unsigned*)hs;     // row = 32 uints (128 B)
    const unsigned* ssu = (const unsigned*)ssrc;   // src pairs

    const int beg = offs[node];
    const int end = offs[node + 1];

    // epilogue operands issued early, in flight during the gather loop
    const unsigned sv = hsu[node * 32 + cp];
    const float dv = dinv[node];
    const float2 bv = *(const float2*)(bias + 2 * cp);

    float2 acc = make_float2(0.f, 0.f);
    const int q0 = beg >> 1;                        // first overlapping pair
    const int npairs = ((end + 1) >> 1) - q0;       // pairs overlapping [beg,end)

    for (int qb = 0; qb < npairs; qb += 16) {
        unsigned ss[16];
#pragma unroll
        for (int j = 0; j < 16; ++j) {
            int q = q0 + qb + j;
            ss[j] = ssu[q <= qmax ? q : qmax];      // clamped: always safe
        }
        unsigned v[16];
#pragma unroll
        for (int j = 0; j < 16; ++j) {
            int s = half ? (int)(ss[j] >> 16) : (int)(ss[j] & 0xFFFFu);
            v[j] = hsu[s * 32 + cp];
        }
#pragma unroll
        for (int j = 0; j < 16; ++j) {
            int e = 2 * (q0 + qb + j) + half;       // edge this lane-half holds
            bool live = (e >= beg) & (e < end);
            acc.x += live ? bf2f((unsigned short)(v[j] & 0xFFFFu)) : 0.f;
            acc.y += live ? bf2f((unsigned short)(v[j] >> 16)) : 0.f;
        }
    }

    // combine the two halves
    acc.x += __shfl_xor(acc.x, 32, 64);
    acc.y += __shfl_xor(acc.y, 32, 64);

    // epilogue: self-loop + scale + bias (+ relu); lanes 0..31 store 256 B
    float rx = dv * (acc.x + bf2f((unsigned short)(sv & 0xFFFFu))) + bv.x;
    float ry = dv * (acc.y + bf2f((unsigned short)(sv >> 16))) + bv.y;
    if (RELU) { rx = fmaxf(rx, 0.f); ry = fmaxf(ry, 0.f); }
    if (half == 0)
        *(float2*)(out + (size_t)node * 64 + 2 * cp) = make_float2(rx, ry);
}

// ---- launch ----------------------------------------------------------------

extern "C" void kernel_launch(void* const* d_in, const int* in_sizes, int n_in,
                              void* d_out, int out_size, void* d_ws, size_t ws_size,
                              hipStream_t stream) {
    const float* x  = (const float*)d_in[0];
    const int*   ei = (const int*)d_in[1];
    const float* W1 = (const float*)d_in[2];
    const float* b1 = (const float*)d_in[3];
    const float* W2 = (const float*)d_in[4];
    const float* b2 = (const float*)d_in[5];

    const int n = in_sizes[0] / 256;   // 50000 (< 65536: ushort src packing)
    const int E = in_sizes[1] / 2;     // 1600000
    const int nb = (n + 63) >> 6;      // 782 buckets
    const int chunk = (E + 255) / 256;
    const int qmax = (E - 2) >> 1;     // last full src-pair index

    // workspace carve-up (256B aligned)
    char* ws = (char*)d_ws;
    auto carve = [&](size_t bytes) {
        void* p = (void*)ws;
        ws += (bytes + 255) & ~(size_t)255;
        return p;
    };
    int*            histT  = (int*)carve((size_t)nb * 256 * 4);
    int*            total  = (int*)carve((size_t)nb * 4);
    int*            base   = (int*)carve((size_t)(nb + 1) * 4);
    unsigned*       packed = (unsigned*)carve((size_t)E * 4);
    unsigned short* ssrc   = (unsigned short*)carve((size_t)E * 2);
    int*            offs   = (int*)carve((size_t)(n + 1) * 4);
    float*          dinv   = (float*)carve((size_t)n * 4);
    unsigned short* hs1    = (unsigned short*)carve((size_t)n * 64 * 2);
    float*          hB     = (float*)carve((size_t)n * 64 * 4);
    unsigned short* hs2    = (unsigned short*)carve((size_t)n * 64 * 2);

    k_hist<<<256, 256, 0, stream>>>(ei, E, nb, chunk, histT);
    k_scan_cols<<<nb, 256, 0, stream>>>(histT, total);
    k_scan_totals<<<1, 1024, 0, stream>>>(total, base, nb);
    k_scatter<<<256, 256, 0, stream>>>(ei, E, nb, chunk, histT, base, packed);
    k_csr<<<nb, 256, 0, stream>>>(packed, base, n, offs, dinv, ssrc);

    const int nbG = (n + 63) / 64;

    // layer 1: hs1 = bf16(dinv*(x@W1)) ; hB = relu(agg + b1)
    k_gemm<256><<<nbG, 256, 0, stream>>>(x, W1, dinv, hs1, n);
    k_agg<true><<<(n + 3) / 4, 256, 0, stream>>>(hs1, offs, ssrc, dinv, b1, hB,
                                                 n, qmax);

    // layer 2: hs2 = bf16(dinv*(hB@W2)) ; out = agg + b2
    k_gemm<64><<<nbG, 256, 0, stream>>>(hB, W2, dinv, hs2, n);
    k_agg<false><<<(n + 3) / 4, 256, 0, stream>>>(hs2, offs, ssrc, dinv, b2,
                                                  (float*)d_out, n, qmax);
}

// Round 10
// 224.316 us; speedup vs baseline: 6.8130x; 1.0717x over previous
//
#include <hip/hip_runtime.h>
#include <hip/hip_bf16.h>

// GCN 2-layer: h1 = relu(Ahat @ (x@W1) + b1); out = Ahat @ (h1@W2) + b2
// Ahat = D^-1/2 (A + I) D^-1/2.
//
// Pipeline (zero global atomics):
//   k_hist/k_scan_cols/k_scan_totals/k_scatter: deterministic bucket partition
//     (bucket = dst>>6) via per-block LDS histograms.
//   k_csr: per bucket -> per-node PAIR-ALIGNED, SENTINEL-PADDED src lists
//     (ssrcp; sentinel src = n -> zero row of hs), qbeg/qcnt, dinv; zeroes
//     hs row n and writes guard pair ssrcp[0..1] = {n,n}.
//   k_gemm: register-tiled 64x64; epilogue writes hs = bf16(dinv * (X@W)).
//   k_agg: wave per node; dual-edge gathers (lane halves = lo/hi edge of a src
//     pair); 16-pair batches, NO masks (sentinels add 0), unclamped scalar
//     index loads (s_load_dwordx8-able); tail batch pads via SALU cselect to
//     the guard pair.
// R3: never funnel E atomics into few global addresses.
// R4: agg needs a huge grid + deep MLP, not per-bucket LDS atomics.
// R5: s_barrier is workgroup-scope; 64-wide scan in wave 0 uses shfl.
// R6: bf16 rows halve gather bytes. R7: 2 edges per gather instr.
// R8: masked full-width batches beat scalar remainder loops.
// R9: index-clamp killed s_load vectorization; live-masks were >half the VALU
//     -> sentinel padding removes both.

#define NB_MAX 1024  // max buckets (n <= 65535 for ushort src packing)

__device__ inline unsigned short f2bf(float f) {      // RNE fp32 -> bf16
    unsigned u = __builtin_bit_cast(unsigned, f);
    return (unsigned short)((u + 0x7FFFu + ((u >> 16) & 1u)) >> 16);
}
__device__ inline float bf2f(unsigned short b) {
    return __builtin_bit_cast(float, (unsigned)b << 16);
}

// ---- 1. per-block bucket histogram ----------------------------------------

__global__ __launch_bounds__(256) void k_hist(const int* __restrict__ ei, int E,
                                              int nb, int chunk,
                                              int* __restrict__ histT) {
    __shared__ int h[NB_MAX];
    for (int i = threadIdx.x; i < nb; i += 256) h[i] = 0;
    __syncthreads();
    int e0 = blockIdx.x * chunk, e1 = min(E, e0 + chunk);
    for (int e = e0 + threadIdx.x; e < e1; e += 256)
        atomicAdd(&h[ei[E + e] >> 6], 1);          // LDS atomic
    __syncthreads();
    for (int b = threadIdx.x; b < nb; b += 256)
        histT[b * 256 + blockIdx.x] = h[b];        // [bucket][block]
}

// ---- 2. scan each bucket's 256 per-block counts ---------------------------

__global__ __launch_bounds__(256) void k_scan_cols(int* __restrict__ histT,
                                                   int* __restrict__ total) {
    __shared__ int sm[256];
    int b = blockIdx.x, t = threadIdx.x;
    int v = histT[b * 256 + t];
    sm[t] = v;
    __syncthreads();
    for (int off = 1; off < 256; off <<= 1) {
        int u = (t >= off) ? sm[t - off] : 0;
        __syncthreads();
        sm[t] += u;
        __syncthreads();
    }
    histT[b * 256 + t] = sm[t] - v;                // exclusive within bucket
    if (t == 255) total[b] = sm[255];
}

// ---- 3. scan bucket totals -> bucket bases --------------------------------

__global__ __launch_bounds__(1024) void k_scan_totals(const int* __restrict__ total,
                                                      int* __restrict__ base, int nb) {
    __shared__ int sm[1024];
    int t = threadIdx.x;
    int v = (t < nb) ? total[t] : 0;
    sm[t] = v;
    __syncthreads();
    for (int off = 1; off < 1024; off <<= 1) {
        int u = (t >= off) ? sm[t - off] : 0;
        __syncthreads();
        sm[t] += u;
        __syncthreads();
    }
    if (t < nb) base[t] = sm[t] - v;               // exclusive
    if (t == nb - 1) base[nb] = sm[t];             // total E
}

// ---- 4. scatter packed edges into bucket-grouped order --------------------

__global__ __launch_bounds__(256) void k_scatter(const int* __restrict__ ei, int E,
                                                 int nb, int chunk,
                                                 const int* __restrict__ histT,
                                                 const int* __restrict__ base,
                                                 unsigned* __restrict__ packed) {
    __shared__ int cur[NB_MAX];
    for (int b = threadIdx.x; b < nb; b += 256)
        cur[b] = base[b] + histT[b * 256 + blockIdx.x];
    __syncthreads();
    int e0 = blockIdx.x * chunk, e1 = min(E, e0 + chunk);
    for (int e = e0 + threadIdx.x; e < e1; e += 256) {
        int s = ei[e], d = ei[E + e];
        int pos = atomicAdd(&cur[d >> 6], 1);      // LDS atomic
        packed[pos] = (unsigned)s | ((unsigned)(d & 63) << 16);
    }
}

// ---- 5. per-bucket padded CSR: qbeg/qcnt (pair units), dinv, ssrcp --------
// Each node's list starts at an even ushort index and is padded to even
// length with sentinel src = n (zero hs row). Bucket b's region starts at
// pb = even(2 + base[b] + 128*b): 128-slot slack > max 64 pads per bucket.

__global__ __launch_bounds__(256) void k_csr(const unsigned* __restrict__ packed,
                                             const int* __restrict__ base,
                                             int n,
                                             int* __restrict__ qbeg,
                                             int* __restrict__ qcnt,
                                             float* __restrict__ dinv,
                                             unsigned short* __restrict__ ssrcp,
                                             unsigned short* __restrict__ hs1,
                                             unsigned short* __restrict__ hs2) {
    __shared__ int cnt[64];
    __shared__ int cur[64];
    const int b = blockIdx.x, t = threadIdx.x;
    const int p0 = base[b], p1 = base[b + 1];
    if (t < 64) cnt[t] = 0;
    __syncthreads();
    for (int p = p0 + t; p < p1; p += 256)
        atomicAdd(&cnt[(packed[p] >> 16) & 63], 1);
    __syncthreads();
    if (t < 64) {                      // wave 0: shuffle scan over padded degs
        int deg = cnt[t];
        int pdeg = (deg + 1) & ~1;     // even-padded degree
        int sum = pdeg;
#pragma unroll
        for (int d = 1; d < 64; d <<= 1) {
            int u = __shfl_up(sum, d, 64);
            if (t >= d) sum += u;
        }
        int excl = sum - pdeg;                       // even
        int pb = (2 + p0 + 128 * b + 1) & ~1;        // even bucket base
        int start = pb + excl;                       // even
        int node = (b << 6) + t;
        if (node < n) {
            qbeg[node] = start >> 1;                 // pair units (>= 1)
            qcnt[node] = pdeg >> 1;
            dinv[node] = 1.0f / sqrtf((float)(deg + 1));  // +1 self-loop
        }
        cur[t] = start;
    }
    __syncthreads();
    for (int p = p0 + t; p < p1; p += 256) {
        unsigned k = packed[p];
        int pos = atomicAdd(&cur[(k >> 16) & 63], 1);
        ssrcp[pos] = (unsigned short)(k & 0xFFFFu);  // ~4 KB window scatter
    }
    __syncthreads();
    if (t < 64 && (cnt[t] & 1))                      // sentinel pad to even
        ssrcp[cur[t]] = (unsigned short)n;
    if (b == 0) {                                    // zero row n + guard pair
        if (t < 64) {
            hs1[(size_t)n * 64 + t] = 0;
            hs2[(size_t)n * 64 + t] = 0;
        }
        if (t == 0) {
            ssrcp[0] = (unsigned short)n;
            ssrcp[1] = (unsigned short)n;
        }
    }
}

// ---- GEMM: HS[n,64] = bf16( dinv[:,None] * (X[n,K] @ W[K,64]) ) ------------
// Register-tiled: block(256) = 64x64 tile; thread = 4x4. dinv pre-scale fused.

#define FMA4(A, s, wv)                                                         \
    (A).x += (s) * (wv).x; (A).y += (s) * (wv).y;                              \
    (A).z += (s) * (wv).z; (A).w += (s) * (wv).w;

template <int K>
__global__ __launch_bounds__(256) void k_gemm(const float* __restrict__ X,
                                              const float* __restrict__ W,
                                              const float* __restrict__ dinv,
                                              unsigned short* __restrict__ HS,
                                              int n) {
    __shared__ float xl[64][36];
    __shared__ float wl[32][64];

    const int t = threadIdx.x;
    const int tc = t & 15;
    const int tr = t >> 4;
    const int row0 = blockIdx.x * 64;

    float4 acc[4];
    acc[0] = acc[1] = acc[2] = acc[3] = make_float4(0.f, 0.f, 0.f, 0.f);

    for (int k0 = 0; k0 < K; k0 += 32) {
#pragma unroll
        for (int i = 0; i < 2; ++i) {
            int idx = i * 256 + t;
            int r = idx >> 3, f4 = idx & 7;
            int gr = row0 + r;
            float4 v = make_float4(0.f, 0.f, 0.f, 0.f);
            if (gr < n) v = *(const float4*)(X + (size_t)gr * K + k0 + f4 * 4);
            *(float4*)&xl[r][f4 * 4] = v;
        }
#pragma unroll
        for (int i = 0; i < 2; ++i) {
            int idx = i * 256 + t;
            int kr = idx >> 4, f4 = idx & 15;
            *(float4*)&wl[kr][f4 * 4] =
                *(const float4*)(W + (size_t)(k0 + kr) * 64 + f4 * 4);
        }
        __syncthreads();

#pragma unroll
        for (int kk = 0; kk < 32; kk += 4) {
            float4 xv0 = *(float4*)&xl[tr * 4 + 0][kk];
            float4 xv1 = *(float4*)&xl[tr * 4 + 1][kk];
            float4 xv2 = *(float4*)&xl[tr * 4 + 2][kk];
            float4 xv3 = *(float4*)&xl[tr * 4 + 3][kk];
            float4 wv0 = *(float4*)&wl[kk + 0][tc * 4];
            float4 wv1 = *(float4*)&wl[kk + 1][tc * 4];
            float4 wv2 = *(float4*)&wl[kk + 2][tc * 4];
            float4 wv3 = *(float4*)&wl[kk + 3][tc * 4];

            FMA4(acc[0], xv0.x, wv0); FMA4(acc[0], xv0.y, wv1);
            FMA4(acc[0], xv0.z, wv2); FMA4(acc[0], xv0.w, wv3);
            FMA4(acc[1], xv1.x, wv0); FMA4(acc[1], xv1.y, wv1);
            FMA4(acc[1], xv1.z, wv2); FMA4(acc[1], xv1.w, wv3);
            FMA4(acc[2], xv2.x, wv0); FMA4(acc[2], xv2.y, wv1);
            FMA4(acc[2], xv2.z, wv2); FMA4(acc[2], xv2.w, wv3);
            FMA4(acc[3], xv3.x, wv0); FMA4(acc[3], xv3.y, wv1);
            FMA4(acc[3], xv3.z, wv2); FMA4(acc[3], xv3.w, wv3);
        }
        __syncthreads();
    }

#pragma unroll
    for (int ri = 0; ri < 4; ++ri) {
        int gr = row0 + tr * 4 + ri;
        if (gr < n) {
            float dv = dinv[gr];
            float4 o = acc[ri];
            ushort4 pk;
            pk.x = f2bf(o.x * dv); pk.y = f2bf(o.y * dv);
            pk.z = f2bf(o.z * dv); pk.w = f2bf(o.w * dv);
            *(ushort4*)(HS + (size_t)gr * 64 + tc * 4) = pk;
        }
    }
}

// ---- 6. aggregation: out[i] = dinv[i]*(sum_src hs[src] + hs[i]) + b -------
// Wave per node. Dual-edge gathers; 16-pair batches; all pairs live (sentinel
// padding), so NO masks; full batches use consecutive scalar index loads;
// tail batch selects dead slots to guard pair 0 via SALU cselect.

template <bool RELU>
__global__ void k_agg(const unsigned short* __restrict__ hs,  // n+1 rows
                      const int* __restrict__ qbeg,
                      const int* __restrict__ qcnt,
                      const unsigned short* __restrict__ ssrcp,
                      const float* __restrict__ dinv,
                      const float* __restrict__ bias,
                      float* __restrict__ out, int n) {
    int node = blockIdx.x * 4 + (threadIdx.x >> 6);
    if (node >= n) return;
    node = __builtin_amdgcn_readfirstlane(node);   // SGPR -> scalar loads
    const int lane = threadIdx.x & 63;
    const int half = lane >> 5;       // lo/hi edge of the pair
    const int cp   = lane & 31;       // channel pair: ch 2cp, 2cp+1

    const unsigned* hsu = (const unsigned*)hs;     // row = 32 uints (128 B)
    const unsigned* ssu = (const unsigned*)ssrcp;  // src pairs

    const int q0 = qbeg[node];
    const int m  = qcnt[node];

    // epilogue operands issued early, in flight during the gather loop
    const unsigned sv = hsu[node * 32 + cp];
    const float dv = dinv[node];
    const float2 bv = *(const float2*)(bias + 2 * cp);

    float ax = 0.f, ay = 0.f;
    int qb = 0;
    for (; qb + 16 <= m; qb += 16) {               // full batches: no selects
        unsigned ss[16];
#pragma unroll
        for (int j = 0; j < 16; ++j) ss[j] = ssu[q0 + qb + j];
        unsigned v[16];
#pragma unroll
        for (int j = 0; j < 16; ++j) {
            int s = half ? (int)(ss[j] >> 16) : (int)(ss[j] & 0xFFFFu);
            v[j] = hsu[s * 32 + cp];
        }
#pragma unroll
        for (int j = 0; j < 16; ++j) {
            ax += __builtin_bit_cast(float, v[j] << 16);
            ay += __builtin_bit_cast(float, v[j] & 0xFFFF0000u);
        }
    }
    const int rem = m - qb;
    if (rem) {                                     // one tail batch, SALU sel
        unsigned ss[16];
#pragma unroll
        for (int j = 0; j < 16; ++j) {
            int q = (j < rem) ? (q0 + qb + j) : 0; // 0 = {n,n} guard pair
            ss[j] = ssu[q];
        }
        unsigned v[16];
#pragma unroll
        for (int j = 0; j < 16; ++j) {
            int s = half ? (int)(ss[j] >> 16) : (int)(ss[j] & 0xFFFFu);
            v[j] = hsu[s * 32 + cp];
        }
#pragma unroll
        for (int j = 0; j < 16; ++j) {
            ax += __builtin_bit_cast(float, v[j] << 16);
            ay += __builtin_bit_cast(float, v[j] & 0xFFFF0000u);
        }
    }

    // combine the two halves
    ax += __shfl_xor(ax, 32, 64);
    ay += __shfl_xor(ay, 32, 64);

    // epilogue: self-loop + scale + bias (+ relu); lanes 0..31 store 256 B
    float rx = dv * (ax + __builtin_bit_cast(float, sv << 16)) + bv.x;
    float ry = dv * (ay + __builtin_bit_cast(float, sv & 0xFFFF0000u)) + bv.y;
    if (RELU) { rx = fmaxf(rx, 0.f); ry = fmaxf(ry, 0.f); }
    if (half == 0)
        *(float2*)(out + (size_t)node * 64 + 2 * cp) = make_float2(rx, ry);
}

// ---- launch ----------------------------------------------------------------

extern "C" void kernel_launch(void* const* d_in, const int* in_sizes, int n_in,
                              void* d_out, int out_size, void* d_ws, size_t ws_size,
                              hipStream_t stream) {
    const float* x  = (const float*)d_in[0];
    const int*   ei = (const int*)d_in[1];
    const float* W1 = (const float*)d_in[2];
    const float* b1 = (const float*)d_in[3];
    const float* W2 = (const float*)d_in[4];
    const float* b2 = (const float*)d_in[5];

    const int n = in_sizes[0] / 256;   // 50000 (< 65536: ushort src packing)
    const int E = in_sizes[1] / 2;     // 1600000
    const int nb = (n + 63) >> 6;      // 782 buckets
    const int chunk = (E + 255) / 256;

    // workspace carve-up (256B aligned)
    char* ws = (char*)d_ws;
    auto carve = [&](size_t bytes) {
        void* p = (void*)ws;
        ws += (bytes + 255) & ~(size_t)255;
        return p;
    };
    int*            histT  = (int*)carve((size_t)nb * 256 * 4);
    int*            total  = (int*)carve((size_t)nb * 4);
    int*            base   = (int*)carve((size_t)(nb + 1) * 4);
    unsigned*       packed = (unsigned*)carve((size_t)E * 4);
    unsigned short* ssrcp  = (unsigned short*)carve(((size_t)E + 128 * nb + 256) * 2);
    int*            qbeg   = (int*)carve((size_t)n * 4);
    int*            qcnt   = (int*)carve((size_t)n * 4);
    float*          dinv   = (float*)carve((size_t)n * 4);
    unsigned short* hs1    = (unsigned short*)carve((size_t)(n + 1) * 64 * 2);
    float*          hB     = (float*)carve((size_t)n * 64 * 4);
    unsigned short* hs2    = (unsigned short*)carve((size_t)(n + 1) * 64 * 2);

    k_hist<<<256, 256, 0, stream>>>(ei, E, nb, chunk, histT);
    k_scan_cols<<<nb, 256, 0, stream>>>(histT, total);
    k_scan_totals<<<1, 1024, 0, stream>>>(total, base, nb);
    k_scatter<<<256, 256, 0, stream>>>(ei, E, nb, chunk, histT, base, packed);
    k_csr<<<nb, 256, 0, stream>>>(packed, base, n, qbeg, qcnt, dinv, ssrcp,
                                  hs1, hs2);

    const int nbG = (n + 63) / 64;

    // layer 1: hs1 = bf16(dinv*(x@W1)) ; hB = relu(agg + b1)
    k_gemm<256><<<nbG, 256, 0, stream>>>(x, W1, dinv, hs1, n);
    k_agg<true><<<(n + 3) / 4, 256, 0, stream>>>(hs1, qbeg, qcnt, ssrcp, dinv,
                                                 b1, hB, n);

    // layer 2: hs2 = bf16(dinv*(hB@W2)) ; out = agg + b2
    k_gemm<64><<<nbG, 256, 0, stream>>>(hB, W2, dinv, hs2, n);
    k_agg<false><<<(n + 3) / 4, 256, 0, stream>>>(hs2, qbeg, qcnt, ssrcp, dinv,
                                                  b2, (float*)d_out, n);
}